// Round 15
// baseline (34.598 us; speedup 1.0000x reference)
//
#include <hip/hip_runtime.h>

#define TPB 128                // 2 waves per block
#define MPW 128                // matrices per tile (2 per lane, v2f)
#define FPT (MPW * 9)          // 1152 floats = 4608 B per tile buffer

typedef float v2f __attribute__((ext_vector_type(2)));
typedef int   v2i __attribute__((ext_vector_type(2)));

typedef __attribute__((address_space(1))) const void gv_t;
typedef __attribute__((address_space(3))) void lv_t;

static __device__ __forceinline__ void dma16(const float* g, float* l){
    __builtin_amdgcn_global_load_lds((gv_t*)g, (lv_t*)l, 16, 0, 0);
}
static __device__ __forceinline__ void dma4(const float* g, float* l){
    __builtin_amdgcn_global_load_lds((gv_t*)g, (lv_t*)l, 4, 0, 0);
}

static __device__ __forceinline__ v2f sqrt2(v2f a){
    v2f r; r.x = __builtin_amdgcn_sqrtf(a.x); r.y = __builtin_amdgcn_sqrtf(a.y); return r;
}
static __device__ __forceinline__ v2f rsq2(v2f a){
    v2f r; r.x = __builtin_amdgcn_rsqf(a.x); r.y = __builtin_amdgcn_rsqf(a.y); return r;
}
static __device__ __forceinline__ v2f csign2(v2f x, v2f y){
    v2f r; r.x = copysignf(x.x, y.x); r.y = copysignf(x.y, y.y); return r;
}
static __device__ __forceinline__ v2f fabs2(v2f x){
    v2f r; r.x = fabsf(x.x); r.y = fabsf(x.y); return r;
}
static __device__ __forceinline__ v2f sel2(v2i m, v2f a, v2f b){
    v2f r; r.x = m.x ? a.x : b.x; r.y = m.y ? a.y : b.y; return r;
}
static __device__ __forceinline__ void rot2(v2f &p, v2f &q, v2f c, v2f s){
    v2f x = p, y = q; p = c*x - s*y; q = s*x + c*y;
}

// Exact cyclic-Jacobi rotation (2 transcendentals), branchless (r7-r14 math).
static __device__ __forceinline__ void jrot2(v2f &app, v2f &aqq, v2f &apq,
                                             v2f &arp, v2f &arq,
                                             v2f &v0p, v2f &v1p, v2f &v2p,
                                             v2f &v0q, v2f &v1q, v2f &v2q)
{
    v2f d   = aqq - app;
    v2f w   = apq + apq;
    v2f nrm = d*d + w*w;
    v2f rr  = sqrt2(nrm);
    v2f sr  = csign2(rr, d);
    v2f den = d + sr;
    v2f inv = rsq2(den*den + w*w);
    v2f c   = fabs2(den) * inv;
    v2f s   = w * csign2(inv, den);
    v2i tiny = nrm < (v2f)1e-30f;
    c = sel2(tiny, (v2f)1.0f, c);
    s = sel2(tiny, (v2f)0.0f, s);
    v2f sum = app + aqq;
    v2f lo  = 0.5f*(sum - sr);
    app = lo; aqq = sum - lo; apq = (v2f)0.0f;
    rot2(arp, arq, c, s);
    rot2(v0p, v0q, c, s);
    rot2(v1p, v1q, c, s);
    rot2(v2p, v2q, c, s);
}

// SO(3) projection, 2 packed matrices (r7 algorithm, verified r7-r14).
static __device__ __forceinline__ void solve2(
    v2f m00, v2f m01, v2f m02,
    v2f m10, v2f m11, v2f m12,
    v2f m20, v2f m21, v2f m22,
    v2f &r00, v2f &r01, v2f &r02,
    v2f &r10, v2f &r11, v2f &r12,
    v2f &r20, v2f &r21, v2f &r22)
{
    v2f a00 = m00*m00 + m10*m10 + m20*m20;
    v2f a11 = m01*m01 + m11*m11 + m21*m21;
    v2f a22 = m02*m02 + m12*m12 + m22*m22;
    v2f a01 = m00*m01 + m10*m11 + m20*m21;
    v2f a02 = m00*m02 + m10*m12 + m20*m22;
    v2f a12 = m01*m02 + m11*m12 + m21*m22;

    v2f v00 = (v2f)1.0f, v01 = (v2f)0.0f, v02 = (v2f)0.0f;
    v2f v10 = (v2f)0.0f, v11 = (v2f)1.0f, v12 = (v2f)0.0f;
    v2f v20 = (v2f)0.0f, v21 = (v2f)0.0f, v22 = (v2f)1.0f;

    #pragma unroll
    for (int sw = 0; sw < 3; ++sw) {
        jrot2(a00, a11, a01, a02, a12, v00, v10, v20, v01, v11, v21);
        jrot2(a00, a22, a02, a01, a12, v00, v10, v20, v02, v12, v22);
        jrot2(a11, a22, a12, a01, a02, v01, v11, v21, v02, v12, v22);
    }

    v2f t;
    {
        v2i c01 = a00 < a11;
        t = a00; a00 = sel2(c01, a11, a00); a11 = sel2(c01, t, a11);
        t = v00; v00 = sel2(c01, v01, v00); v01 = sel2(c01, -t, v01);
        t = v10; v10 = sel2(c01, v11, v10); v11 = sel2(c01, -t, v11);
        t = v20; v20 = sel2(c01, v21, v20); v21 = sel2(c01, -t, v21);
    }
    {
        v2i c02 = a00 < a22;
        t = a00; a00 = sel2(c02, a22, a00); a22 = sel2(c02, t, a22);
        t = v00; v00 = sel2(c02, v02, v00); v02 = sel2(c02, -t, v02);
        t = v10; v10 = sel2(c02, v12, v10); v12 = sel2(c02, -t, v12);
        t = v20; v20 = sel2(c02, v22, v20); v22 = sel2(c02, -t, v22);
    }
    {
        v2i c12 = a11 < a22;
        t = a11; a11 = sel2(c12, a22, a11); a22 = sel2(c12, t, a22);
        t = v01; v01 = sel2(c12, v02, v01); v02 = sel2(c12, -t, v02);
        t = v11; v11 = sel2(c12, v12, v11); v12 = sel2(c12, -t, v12);
        t = v21; v21 = sel2(c12, v22, v21); v22 = sel2(c12, -t, v22);
    }

    v2f b00 = m00*v00 + m01*v10 + m02*v20;
    v2f b10 = m10*v00 + m11*v10 + m12*v20;
    v2f b20 = m20*v00 + m21*v10 + m22*v20;
    v2f b01 = m00*v01 + m01*v11 + m02*v21;
    v2f b11 = m10*v01 + m11*v11 + m12*v21;
    v2f b21 = m20*v01 + m21*v11 + m22*v21;

    v2f n1 = b00*b00 + b10*b10 + b20*b20;
    v2f i1 = rsq2(n1);
    v2i ok1 = n1 > (v2f)1e-30f;
    i1 = sel2(ok1, i1, (v2f)0.0f);
    v2f u00 = b00*i1, u10 = b10*i1, u20 = b20*i1;

    v2f d12 = b01*u00 + b11*u10 + b21*u20;
    v2f q0 = b01 - d12*u00;
    v2f q1 = b11 - d12*u10;
    v2f q2 = b21 - d12*u20;
    v2f n2 = q0*q0 + q1*q1 + q2*q2;
    v2f i2 = rsq2(n2);
    v2i ok2 = n2 > (v2f)1e-30f;
    i2 = sel2(ok2, i2, (v2f)0.0f);
    v2f u01 = q0*i2, u11 = q1*i2, u21 = q2*i2;

    v2f u02 = u10*u21 - u20*u11;
    v2f u12 = u20*u01 - u00*u21;
    v2f u22 = u00*u11 - u10*u01;

    r00 = u00*v00 + u01*v01 + u02*v02;
    r01 = u00*v10 + u01*v11 + u02*v12;
    r02 = u00*v20 + u01*v21 + u02*v22;
    r10 = u10*v00 + u11*v01 + u12*v02;
    r11 = u10*v10 + u11*v11 + u12*v12;
    r12 = u10*v20 + u11*v21 + u12*v22;
    r20 = u20*v00 + u21*v01 + u22*v02;
    r21 = u20*v10 + u21*v11 + u22*v12;
    r22 = u20*v20 + u21*v21 + u22*v22;
}

static __device__ __forceinline__ void issue_dma(const float* __restrict__ x,
                                                 long fb, int lane, float* D)
{
    dma16(x + fb +        lane * 4, &D[0]);
    dma16(x + fb +  256 + lane * 4, &D[256]);
    dma16(x + fb +  512 + lane * 4, &D[512]);
    dma16(x + fb +  768 + lane * 4, &D[768]);
    dma4 (x + fb + 1024 + lane,     &D[1024]);
    dma4 (x + fb + 1088 + lane,     &D[1088]);
}

// 2-DEEP tri-buffer DMA pipeline (the r14 structure, one phase deeper).
// Rationale (r13/r14 post-mortem): dur == issue + 17us memory, serial. Per CU
// an iteration needs ~3us of HBM service but only ~1.5us of compute — a
// 1-deep vmcnt pipeline must block every iteration. Giving every DMA and
// store TWO compute phases to drain lets memory run concurrently.
//  - 3 rotating 4.6 KB buffers/wave; DMA(k+2) issued into the buffer freed
//    two iterations ago (program order guarantees its readout completed).
//  - steady-state wait after stores: vmcnt(16) = keep [st(k-1),DMA(k+2),
//    st(k)] in flight, drain exactly DMA(k+1) (next iter's input). FIFO-safe.
//  - no __syncthreads; in-order per-wave DS pipe (validated r9/r13/r14).
//  - NO launch-bounds min-wave cap (r9/r10: caps spill).
__global__ __launch_bounds__(TPB) void svdo_kernel(const float* __restrict__ x,
                                                   float* __restrict__ out,
                                                   int nmat, int ntiles, int W)
{
    __shared__ float lds[2][3][FPT];     // 27648 B / block -> 5 blocks/CU
    const int lane = threadIdx.x & 63;
    const int wv   = threadIdx.x >> 6;

    int t_cur = blockIdx.x * 2 + wv;
    if (t_cur >= ntiles) return;

    float* B0 = lds[wv][0];
    float* B1 = lds[wv][1];
    float* B2 = lds[wv][2];

    bool full_cur = (long)(t_cur + 1) * MPW <= (long)nmat;
    int  t_nxt = t_cur + W;
    bool full_nxt = full_cur && (t_nxt < ntiles) &&
                    ((long)(t_nxt + 1) * MPW <= (long)nmat);

    if (full_cur) {
        // Prologue: DMA tile k into B0, tile k+1 into B1 (2-deep from start).
        issue_dma(x, (long)t_cur * FPT, lane, B0);
        if (full_nxt) issue_dma(x, (long)t_nxt * FPT, lane, B1);
        if (full_nxt) { asm volatile("s_waitcnt vmcnt(6)" ::: "memory"); }
        else          { asm volatile("s_waitcnt vmcnt(0)" ::: "memory"); }

        for (;;) {
            // ---- invariant: DMA(t_cur) landed in B0 ----
            // 1. Load M fragments (stride-9 b32: 2 lanes/bank, free).
            const float* p0 = &B0[lane * 9];
            const float* p1 = &B0[(lane + 64) * 9];
            v2f m00 = {p0[0], p1[0]}, m01 = {p0[1], p1[1]}, m02 = {p0[2], p1[2]};
            v2f m10 = {p0[3], p1[3]}, m11 = {p0[4], p1[4]}, m12 = {p0[5], p1[5]};
            v2f m20 = {p0[6], p1[6]}, m21 = {p0[7], p1[7]}, m22 = {p0[8], p1[8]};

            // 2. Issue DMA for tile k+2 into B2 (freed two iterations ago;
            //    its readout ds_reads completed before these are issued).
            const int  t_fut   = t_nxt + W;
            const bool full_fut = full_nxt && (t_fut < ntiles) &&
                                  ((long)(t_fut + 1) * MPW <= (long)nmat);
            if (full_fut) issue_dma(x, (long)t_fut * FPT, lane, B2);

            // 3. Solve.
            v2f r00, r01, r02, r10, r11, r12, r20, r21, r22;
            solve2(m00, m01, m02, m10, m11, m12, m20, m21, m22,
                   r00, r01, r02, r10, r11, r12, r20, r21, r22);

            // 4. Stage results into B0 (input already consumed).
            float* o0 = &B0[lane * 9];
            o0[0]=r00.x; o0[1]=r01.x; o0[2]=r02.x;
            o0[3]=r10.x; o0[4]=r11.x; o0[5]=r12.x;
            o0[6]=r20.x; o0[7]=r21.x; o0[8]=r22.x;
            float* o1 = &B0[(lane + 64) * 9];
            o1[0]=r00.y; o1[1]=r01.y; o1[2]=r02.y;
            o1[3]=r10.y; o1[4]=r11.y; o1[5]=r12.y;
            o1[6]=r20.y; o1[7]=r21.y; o1[8]=r22.y;
            asm volatile("" ::: "memory");   // keep write->read order at IR level

            // 5. Coalesced readout + stores (fire-and-forget, 2 phases to drain).
            {
                const long fb = (long)t_cur * FPT;
                float4 s0 = *(const float4*)&B0[(lane       ) * 4];
                float4 s1 = *(const float4*)&B0[(lane +  64) * 4];
                float4 s2 = *(const float4*)&B0[(lane + 128) * 4];
                float4 s3 = *(const float4*)&B0[(lane + 192) * 4];
                *(float4*)(out + fb + (lane       ) * 4) = s0;
                *(float4*)(out + fb + (lane +  64) * 4) = s1;
                *(float4*)(out + fb + (lane + 128) * 4) = s2;
                *(float4*)(out + fb + (lane + 192) * 4) = s3;
                if (lane < 32) {
                    float4 s4 = *(const float4*)&B0[(lane + 256) * 4];
                    *(float4*)(out + fb + (lane + 256) * 4) = s4;
                }
            }

            if (!full_nxt) break;   // t_nxt absent or partial -> exit pipeline

            // 6. Rotate buffers / advance.
            float* tmp = B0; B0 = B1; B1 = B2; B2 = tmp;
            t_cur = t_nxt; t_nxt = t_fut;
            const bool nf = full_fut;   // full_nxt for the next iteration
            // 7. Drain DMA(new t_cur) only; keep [st(k-1),DMA(k+2),st(k)]:
            if (nf) { asm volatile("s_waitcnt vmcnt(16)" ::: "memory"); }
            else    { asm volatile("s_waitcnt vmcnt(10)" ::: "memory"); }
            full_nxt = nf;
        }

        // Pipeline exited after storing t_cur. If t_nxt exists it is partial.
        if (!(t_nxt < ntiles)) return;
        t_cur = t_nxt;
        // fall through to bounded tail path for the single partial tile
    }

    // Bounded tail path (at most one partial tile; never taken at nmat=2M).
    {
        const long ntotf = (long)nmat * 9;
        const long fb = (long)t_cur * FPT;
        float* L = lds[wv][0];
        for (int idx = lane; idx < FPT; idx += 64) {
            long f = fb + idx;
            L[idx] = (f < ntotf) ? x[f] : 0.0f;
        }
        asm volatile("s_waitcnt vmcnt(0) lgkmcnt(0)" ::: "memory");

        const float* p0 = &L[lane * 9];
        const float* p1 = &L[(lane + 64) * 9];
        v2f m00 = {p0[0], p1[0]}, m01 = {p0[1], p1[1]}, m02 = {p0[2], p1[2]};
        v2f m10 = {p0[3], p1[3]}, m11 = {p0[4], p1[4]}, m12 = {p0[5], p1[5]};
        v2f m20 = {p0[6], p1[6]}, m21 = {p0[7], p1[7]}, m22 = {p0[8], p1[8]};
        v2f r00, r01, r02, r10, r11, r12, r20, r21, r22;
        solve2(m00, m01, m02, m10, m11, m12, m20, m21, m22,
               r00, r01, r02, r10, r11, r12, r20, r21, r22);
        float* o0 = &L[lane * 9];
        o0[0]=r00.x; o0[1]=r01.x; o0[2]=r02.x;
        o0[3]=r10.x; o0[4]=r11.x; o0[5]=r12.x;
        o0[6]=r20.x; o0[7]=r21.x; o0[8]=r22.x;
        float* o1 = &L[(lane + 64) * 9];
        o1[0]=r00.y; o1[1]=r01.y; o1[2]=r02.y;
        o1[3]=r10.y; o1[4]=r11.y; o1[5]=r12.y;
        o1[6]=r20.y; o1[7]=r21.y; o1[8]=r22.y;
        asm volatile("s_waitcnt lgkmcnt(0)" ::: "memory");

        for (int idx = lane; idx < FPT; idx += 64) {
            long f = fb + idx;
            if (f < ntotf) out[f] = L[idx];
        }
    }
}

extern "C" void kernel_launch(void* const* d_in, const int* in_sizes, int n_in,
                              void* d_out, int out_size, void* d_ws, size_t ws_size,
                              hipStream_t stream)
{
    (void)n_in; (void)d_ws; (void)ws_size; (void)out_size;
    const float* x = (const float*)d_in[0];
    float* out = (float*)d_out;
    const int nmat = in_sizes[0] / 9;
    const int ntiles = (nmat + MPW - 1) / MPW;
    int grid = (ntiles + 1) / 2;
    if (grid > 1280) grid = 1280;   // 5 blocks/CU resident, ~6 tiles/wave
    const int W = grid * 2;         // total waves = tile stride
    svdo_kernel<<<grid, TPB, 0, stream>>>(x, out, nmat, ntiles, W);
}

// Round 17
// 30.400 us; speedup vs baseline: 1.1381x; 1.1381x over previous
//
#include <hip/hip_runtime.h>

#define TPB 256
#define MPW 128                // matrices per tile (2 per lane, v2f)
#define FPT (MPW * 9)          // 1152 floats = 4608 B per tile

typedef float v2f __attribute__((ext_vector_type(2)));
typedef int   v2i __attribute__((ext_vector_type(2)));
typedef float f4v __attribute__((ext_vector_type(4)));   // native vec for nt store

typedef __attribute__((address_space(1))) const void gv_t;
typedef __attribute__((address_space(3))) void lv_t;

static __device__ __forceinline__ void dma16(const float* g, float* l){
    __builtin_amdgcn_global_load_lds((gv_t*)g, (lv_t*)l, 16, 0, 0);
}
static __device__ __forceinline__ void dma4(const float* g, float* l){
    __builtin_amdgcn_global_load_lds((gv_t*)g, (lv_t*)l, 4, 0, 0);
}
static __device__ __forceinline__ void st_nt(float* p, f4v v){
    __builtin_nontemporal_store(v, (f4v*)p);
}

static __device__ __forceinline__ v2f sqrt2(v2f a){
    v2f r; r.x = __builtin_amdgcn_sqrtf(a.x); r.y = __builtin_amdgcn_sqrtf(a.y); return r;
}
static __device__ __forceinline__ v2f rsq2(v2f a){
    v2f r; r.x = __builtin_amdgcn_rsqf(a.x); r.y = __builtin_amdgcn_rsqf(a.y); return r;
}
static __device__ __forceinline__ v2f csign2(v2f x, v2f y){
    v2f r; r.x = copysignf(x.x, y.x); r.y = copysignf(x.y, y.y); return r;
}
static __device__ __forceinline__ v2f fabs2(v2f x){
    v2f r; r.x = fabsf(x.x); r.y = fabsf(x.y); return r;
}
static __device__ __forceinline__ v2f sel2(v2i m, v2f a, v2f b){
    v2f r; r.x = m.x ? a.x : b.x; r.y = m.y ? a.y : b.y; return r;
}
static __device__ __forceinline__ void rot2(v2f &p, v2f &q, v2f c, v2f s){
    v2f x = p, y = q; p = c*x - s*y; q = s*x + c*y;
}

// Exact cyclic-Jacobi rotation (2 transcendentals), branchless (r7-r15 math).
static __device__ __forceinline__ void jrot2(v2f &app, v2f &aqq, v2f &apq,
                                             v2f &arp, v2f &arq,
                                             v2f &v0p, v2f &v1p, v2f &v2p,
                                             v2f &v0q, v2f &v1q, v2f &v2q)
{
    v2f d   = aqq - app;
    v2f w   = apq + apq;
    v2f nrm = d*d + w*w;
    v2f rr  = sqrt2(nrm);
    v2f sr  = csign2(rr, d);
    v2f den = d + sr;
    v2f inv = rsq2(den*den + w*w);
    v2f c   = fabs2(den) * inv;
    v2f s   = w * csign2(inv, den);
    v2i tiny = nrm < (v2f)1e-30f;
    c = sel2(tiny, (v2f)1.0f, c);
    s = sel2(tiny, (v2f)0.0f, s);
    v2f sum = app + aqq;
    v2f lo  = 0.5f*(sum - sr);
    app = lo; aqq = sum - lo; apq = (v2f)0.0f;
    rot2(arp, arq, c, s);
    rot2(v0p, v0q, c, s);
    rot2(v1p, v1q, c, s);
    rot2(v2p, v2q, c, s);
}

// SO(3) projection for 2 packed matrices (r7 algorithm, verified r7-r15 —
// reverted verbatim to the r14 text, fixing r16's transcription typo):
// V from 3 Jacobi sweeps; U via Gram-Schmidt on b1,b2 + u3 = u1 x u2.
static __device__ __forceinline__ void solve2(
    v2f m00, v2f m01, v2f m02,
    v2f m10, v2f m11, v2f m12,
    v2f m20, v2f m21, v2f m22,
    v2f &r00, v2f &r01, v2f &r02,
    v2f &r10, v2f &r11, v2f &r12,
    v2f &r20, v2f &r21, v2f &r22)
{
    v2f a00 = m00*m00 + m10*m10 + m20*m20;
    v2f a11 = m01*m01 + m11*m11 + m21*m21;
    v2f a22 = m02*m02 + m12*m12 + m22*m22;
    v2f a01 = m00*m01 + m10*m11 + m20*m21;
    v2f a02 = m00*m02 + m10*m12 + m20*m22;
    v2f a12 = m01*m02 + m11*m12 + m21*m22;

    v2f v00 = (v2f)1.0f, v01 = (v2f)0.0f, v02 = (v2f)0.0f;
    v2f v10 = (v2f)0.0f, v11 = (v2f)1.0f, v12 = (v2f)0.0f;
    v2f v20 = (v2f)0.0f, v21 = (v2f)0.0f, v22 = (v2f)1.0f;

    #pragma unroll
    for (int sw = 0; sw < 3; ++sw) {
        jrot2(a00, a11, a01, a02, a12, v00, v10, v20, v01, v11, v21);
        jrot2(a00, a22, a02, a01, a12, v00, v10, v20, v02, v12, v22);
        jrot2(a11, a22, a12, a01, a02, v01, v11, v21, v02, v12, v22);
    }

    v2f t;
    {
        v2i c01 = a00 < a11;
        t = a00; a00 = sel2(c01, a11, a00); a11 = sel2(c01, t, a11);
        t = v00; v00 = sel2(c01, v01, v00); v01 = sel2(c01, -t, v01);
        t = v10; v10 = sel2(c01, v11, v10); v11 = sel2(c01, -t, v11);
        t = v20; v20 = sel2(c01, v21, v20); v21 = sel2(c01, -t, v21);
    }
    {
        v2i c02 = a00 < a22;
        t = a00; a00 = sel2(c02, a22, a00); a22 = sel2(c02, t, a22);
        t = v00; v00 = sel2(c02, v02, v00); v02 = sel2(c02, -t, v02);
        t = v10; v10 = sel2(c02, v12, v10); v12 = sel2(c02, -t, v12);
        t = v20; v20 = sel2(c02, v22, v20); v22 = sel2(c02, -t, v22);
    }
    {
        v2i c12 = a11 < a22;
        t = a11; a11 = sel2(c12, a22, a11); a22 = sel2(c12, t, a22);
        t = v01; v01 = sel2(c12, v02, v01); v02 = sel2(c12, -t, v02);
        t = v11; v11 = sel2(c12, v12, v11); v12 = sel2(c12, -t, v12);
        t = v21; v21 = sel2(c12, v22, v21); v22 = sel2(c12, -t, v22);
    }

    v2f b00 = m00*v00 + m01*v10 + m02*v20;
    v2f b10 = m10*v00 + m11*v10 + m12*v20;
    v2f b20 = m20*v00 + m21*v10 + m22*v20;
    v2f b01 = m00*v01 + m01*v11 + m02*v21;
    v2f b11 = m10*v01 + m11*v11 + m12*v21;
    v2f b21 = m20*v01 + m21*v11 + m22*v21;

    v2f n1 = b00*b00 + b10*b10 + b20*b20;
    v2f i1 = rsq2(n1);
    v2i ok1 = n1 > (v2f)1e-30f;
    i1 = sel2(ok1, i1, (v2f)0.0f);
    v2f u00 = b00*i1, u10 = b10*i1, u20 = b20*i1;

    v2f d12 = b01*u00 + b11*u10 + b21*u20;
    v2f q0 = b01 - d12*u00;
    v2f q1 = b11 - d12*u10;
    v2f q2 = b21 - d12*u20;
    v2f n2 = q0*q0 + q1*q1 + q2*q2;
    v2f i2 = rsq2(n2);
    v2i ok2 = n2 > (v2f)1e-30f;
    i2 = sel2(ok2, i2, (v2f)0.0f);
    v2f u01 = q0*i2, u11 = q1*i2, u21 = q2*i2;

    v2f u02 = u10*u21 - u20*u11;
    v2f u12 = u20*u01 - u00*u21;
    v2f u22 = u00*u11 - u10*u01;

    r00 = u00*v00 + u01*v01 + u02*v02;
    r01 = u00*v10 + u01*v11 + u02*v12;
    r02 = u00*v20 + u01*v21 + u02*v22;
    r10 = u10*v00 + u11*v01 + u12*v02;
    r11 = u10*v10 + u11*v11 + u12*v12;
    r12 = u10*v20 + u11*v21 + u12*v22;
    r20 = u20*v00 + u21*v01 + u22*v02;
    r21 = u20*v10 + u21*v11 + u22*v12;
    r22 = u20*v20 + u21*v21 + u22*v22;
}

// r14 structure (best: 32.05 us) + ONE change: output stores are
// NON-TEMPORAL (nt cache hint, via native ext_vector_type float4).
// Rationale: every best round clusters at ~4.5 TB/s aggregate (144 MB/dur)
// — a mixed read/write stream ceiling. Output is write-once dead data;
// caching it evicts the 72 MB input from L3 between graph replays, forcing
// HBM re-fetch AND keeping HBM in mixed read/write mode. nt stores leave
// L3 to the input -> replay reads become L3 hits; HBM sees a nearly pure
// write stream (fillBuffer sustains 6.7-6.9 TB/s in that mode vs our 4.5).
__global__ __launch_bounds__(TPB) void svdo_kernel(const float* __restrict__ x,
                                                   float* __restrict__ out,
                                                   int nmat, int ntiles, int W)
{
    __shared__ float lds[4][2][FPT];     // 36864 B / block
    const int lane = threadIdx.x & 63;
    const int wv   = threadIdx.x >> 6;

    int tile = blockIdx.x * 4 + wv;
    if (tile >= ntiles) return;

    int cur = 0;
    bool full = (long)(tile + 1) * MPW <= (long)nmat;

    if (full) {
        {   // prologue: DMA tile -> buf0, drain
            const long fb = (long)tile * FPT;
            float* D = lds[wv][0];
            dma16(x + fb +        lane * 4, &D[0]);
            dma16(x + fb +  256 + lane * 4, &D[256]);
            dma16(x + fb +  512 + lane * 4, &D[512]);
            dma16(x + fb +  768 + lane * 4, &D[768]);
            dma4 (x + fb + 1024 + lane,     &D[1024]);
            dma4 (x + fb + 1088 + lane,     &D[1088]);
            asm volatile("s_waitcnt vmcnt(0)" ::: "memory");
        }

        for (;;) {
            const int  nxt   = tile + W;
            const bool have  = nxt < ntiles;
            const bool nfull = have && ((long)(nxt + 1) * MPW <= (long)nmat);

            if (nfull) {   // issue next tile's 6 DMA ops into other buffer
                const long fb = (long)nxt * FPT;
                float* D = lds[wv][cur ^ 1];
                dma16(x + fb +        lane * 4, &D[0]);
                dma16(x + fb +  256 + lane * 4, &D[256]);
                dma16(x + fb +  512 + lane * 4, &D[512]);
                dma16(x + fb +  768 + lane * 4, &D[768]);
                dma4 (x + fb + 1024 + lane,     &D[1024]);
                dma4 (x + fb + 1088 + lane,     &D[1088]);
            }

            // Compute 2 matrices from buf[cur] (stride-9 b32: 2/bank, free).
            float* L = lds[wv][cur];
            {
                const float* p0 = &L[lane * 9];
                const float* p1 = &L[(lane + 64) * 9];
                v2f m00 = {p0[0], p1[0]}, m01 = {p0[1], p1[1]}, m02 = {p0[2], p1[2]};
                v2f m10 = {p0[3], p1[3]}, m11 = {p0[4], p1[4]}, m12 = {p0[5], p1[5]};
                v2f m20 = {p0[6], p1[6]}, m21 = {p0[7], p1[7]}, m22 = {p0[8], p1[8]};

                v2f r00, r01, r02, r10, r11, r12, r20, r21, r22;
                solve2(m00, m01, m02, m10, m11, m12, m20, m21, m22,
                       r00, r01, r02, r10, r11, r12, r20, r21, r22);

                float* o0 = &L[lane * 9];
                o0[0]=r00.x; o0[1]=r01.x; o0[2]=r02.x;
                o0[3]=r10.x; o0[4]=r11.x; o0[5]=r12.x;
                o0[6]=r20.x; o0[7]=r21.x; o0[8]=r22.x;
                float* o1 = &L[(lane + 64) * 9];
                o1[0]=r00.y; o1[1]=r01.y; o1[2]=r02.y;
                o1[3]=r10.y; o1[4]=r11.y; o1[5]=r12.y;
                o1[6]=r20.y; o1[7]=r21.y; o1[8]=r22.y;
            }
            // Order writeback (ds_write) before cross-lane readout (ds_read):
            // compile-time fence; in-order per-wave DS pipe does the rest.
            asm volatile("" ::: "memory");

            // Coalesced readout + NON-TEMPORAL stores (fire-and-forget).
            {
                const long fb = (long)tile * FPT;
                f4v s0 = *(const f4v*)&L[(lane       ) * 4];
                f4v s1 = *(const f4v*)&L[(lane +  64) * 4];
                f4v s2 = *(const f4v*)&L[(lane + 128) * 4];
                f4v s3 = *(const f4v*)&L[(lane + 192) * 4];
                st_nt(out + fb + (lane       ) * 4, s0);
                st_nt(out + fb + (lane +  64) * 4, s1);
                st_nt(out + fb + (lane + 128) * 4, s2);
                st_nt(out + fb + (lane + 192) * 4, s3);
                if (lane < 32) {
                    f4v s4 = *(const f4v*)&L[(lane + 256) * 4];
                    st_nt(out + fb + (lane + 256) * 4, s4);
                }
            }

            // Drain the next tile's 6 DMA ops (older than the stores); keep
            // the 5 newest vmem ops (this iteration's stores) in flight.
            asm volatile("s_waitcnt vmcnt(5)" ::: "memory");

            if (!have) return;
            tile = nxt;
            if (!nfull) break;     // last (partial) tile -> bounded path
            cur ^= 1;
        }
    }

    // Bounded tail path (at most one partial tile; not taken at nmat=2M).
    {
        const long ntotf = (long)nmat * 9;
        const long fb = (long)tile * FPT;
        float* L = lds[wv][0];
        for (int idx = lane; idx < FPT; idx += 64) {
            long f = fb + idx;
            L[idx] = (f < ntotf) ? x[f] : 0.0f;
        }
        asm volatile("s_waitcnt vmcnt(0) lgkmcnt(0)" ::: "memory");

        const float* p0 = &L[lane * 9];
        const float* p1 = &L[(lane + 64) * 9];
        v2f m00 = {p0[0], p1[0]}, m01 = {p0[1], p1[1]}, m02 = {p0[2], p1[2]};
        v2f m10 = {p0[3], p1[3]}, m11 = {p0[4], p1[4]}, m12 = {p0[5], p1[5]};
        v2f m20 = {p0[6], p1[6]}, m21 = {p0[7], p1[7]}, m22 = {p0[8], p1[8]};
        v2f r00, r01, r02, r10, r11, r12, r20, r21, r22;
        solve2(m00, m01, m02, m10, m11, m12, m20, m21, m22,
               r00, r01, r02, r10, r11, r12, r20, r21, r22);
        float* o0 = &L[lane * 9];
        o0[0]=r00.x; o0[1]=r01.x; o0[2]=r02.x;
        o0[3]=r10.x; o0[4]=r11.x; o0[5]=r12.x;
        o0[6]=r20.x; o0[7]=r21.x; o0[8]=r22.x;
        float* o1 = &L[(lane + 64) * 9];
        o1[0]=r00.y; o1[1]=r01.y; o1[2]=r02.y;
        o1[3]=r10.y; o1[4]=r11.y; o1[5]=r12.y;
        o1[6]=r20.y; o1[7]=r21.y; o1[8]=r22.y;
        asm volatile("s_waitcnt lgkmcnt(0)" ::: "memory");

        for (int idx = lane; idx < FPT; idx += 64) {
            long f = fb + idx;
            if (f < ntotf) out[f] = L[idx];
        }
    }
}

extern "C" void kernel_launch(void* const* d_in, const int* in_sizes, int n_in,
                              void* d_out, int out_size, void* d_ws, size_t ws_size,
                              hipStream_t stream)
{
    (void)n_in; (void)d_ws; (void)ws_size; (void)out_size;
    const float* x = (const float*)d_in[0];
    float* out = (float*)d_out;
    const int nmat = in_sizes[0] / 9;
    const int ntiles = (nmat + MPW - 1) / MPW;
    int grid = (ntiles + 3) / 4;
    if (grid > 1024) grid = 1024;   // 4 blocks/CU resident (LDS), ~3.8 tiles/wave
    const int W = grid * 4;         // total waves = tile stride
    svdo_kernel<<<grid, TPB, 0, stream>>>(x, out, nmat, ntiles, W);
}

// Round 19
// 30.112 us; speedup vs baseline: 1.1490x; 1.0096x over previous
//
#include <hip/hip_runtime.h>

#define TPB 256
#define MPW 128                // matrices per tile (2 per lane, v2f)
#define FPT (MPW * 9)          // 1152 floats = 4608 B per tile

typedef float v2f __attribute__((ext_vector_type(2)));
typedef int   v2i __attribute__((ext_vector_type(2)));
typedef float f4v __attribute__((ext_vector_type(4)));   // native vec for nt store

typedef __attribute__((address_space(1))) const void gv_t;
typedef __attribute__((address_space(3))) void lv_t;

static __device__ __forceinline__ void dma16(const float* g, float* l){
    __builtin_amdgcn_global_load_lds((gv_t*)g, (lv_t*)l, 16, 0, 0);
}
static __device__ __forceinline__ void dma4(const float* g, float* l){
    __builtin_amdgcn_global_load_lds((gv_t*)g, (lv_t*)l, 4, 0, 0);
}
static __device__ __forceinline__ void st_nt(float* p, f4v v){
    __builtin_nontemporal_store(v, (f4v*)p);
}

static __device__ __forceinline__ v2f sqrt2(v2f a){
    v2f r; r.x = __builtin_amdgcn_sqrtf(a.x); r.y = __builtin_amdgcn_sqrtf(a.y); return r;
}
static __device__ __forceinline__ v2f rsq2(v2f a){
    v2f r; r.x = __builtin_amdgcn_rsqf(a.x); r.y = __builtin_amdgcn_rsqf(a.y); return r;
}
static __device__ __forceinline__ v2f csign2(v2f x, v2f y){
    v2f r; r.x = copysignf(x.x, y.x); r.y = copysignf(x.y, y.y); return r;
}
static __device__ __forceinline__ v2f fabs2(v2f x){
    v2f r; r.x = fabsf(x.x); r.y = fabsf(x.y); return r;
}
static __device__ __forceinline__ v2f sel2(v2i m, v2f a, v2f b){
    v2f r; r.x = m.x ? a.x : b.x; r.y = m.y ? a.y : b.y; return r;
}
static __device__ __forceinline__ void rot2(v2f &p, v2f &q, v2f c, v2f s){
    v2f x = p, y = q; p = c*x - s*y; q = s*x + c*y;
}

// Exact cyclic-Jacobi rotation (2 transcendentals), branchless (r7-r17 math).
static __device__ __forceinline__ void jrot2(v2f &app, v2f &aqq, v2f &apq,
                                             v2f &arp, v2f &arq,
                                             v2f &v0p, v2f &v1p, v2f &v2p,
                                             v2f &v0q, v2f &v1q, v2f &v2q)
{
    v2f d   = aqq - app;
    v2f w   = apq + apq;
    v2f nrm = d*d + w*w;
    v2f rr  = sqrt2(nrm);
    v2f sr  = csign2(rr, d);
    v2f den = d + sr;
    v2f inv = rsq2(den*den + w*w);
    v2f c   = fabs2(den) * inv;
    v2f s   = w * csign2(inv, den);
    v2i tiny = nrm < (v2f)1e-30f;
    c = sel2(tiny, (v2f)1.0f, c);
    s = sel2(tiny, (v2f)0.0f, s);
    v2f sum = app + aqq;
    v2f lo  = 0.5f*(sum - sr);
    app = lo; aqq = sum - lo; apq = (v2f)0.0f;
    rot2(arp, arq, c, s);
    rot2(v0p, v0q, c, s);
    rot2(v1p, v1q, c, s);
    rot2(v2p, v2q, c, s);
}

// SO(3) projection for 2 packed matrices. 3 Jacobi sweeps (REVERTED from
// r18's 2 — measured: 2 sweeps -> absmax 0.15, fail; 3 sweeps -> error floor).
// ONE change vs r17: the eigenvalue sort is reduced from a full 3-way
// descending sort to MIN-TO-COLUMN-3 (2 compare-swaps). GS conditioning only
// requires that the two columns fed to Gram-Schmidt be the two largest-sigma
// columns, in either order; each swap negates the outgoing column so
// det(V)=+1 is preserved.
static __device__ __forceinline__ void solve2(
    v2f m00, v2f m01, v2f m02,
    v2f m10, v2f m11, v2f m12,
    v2f m20, v2f m21, v2f m22,
    v2f &r00, v2f &r01, v2f &r02,
    v2f &r10, v2f &r11, v2f &r12,
    v2f &r20, v2f &r21, v2f &r22)
{
    v2f a00 = m00*m00 + m10*m10 + m20*m20;
    v2f a11 = m01*m01 + m11*m11 + m21*m21;
    v2f a22 = m02*m02 + m12*m12 + m22*m22;
    v2f a01 = m00*m01 + m10*m11 + m20*m21;
    v2f a02 = m00*m02 + m10*m12 + m20*m22;
    v2f a12 = m01*m02 + m11*m12 + m21*m22;

    v2f v00 = (v2f)1.0f, v01 = (v2f)0.0f, v02 = (v2f)0.0f;
    v2f v10 = (v2f)0.0f, v11 = (v2f)1.0f, v12 = (v2f)0.0f;
    v2f v20 = (v2f)0.0f, v21 = (v2f)0.0f, v22 = (v2f)1.0f;

    #pragma unroll
    for (int sw = 0; sw < 3; ++sw) {
        jrot2(a00, a11, a01, a02, a12, v00, v10, v20, v01, v11, v21);
        jrot2(a00, a22, a02, a01, a12, v00, v10, v20, v02, v12, v22);
        jrot2(a11, a22, a12, a01, a02, v01, v11, v21, v02, v12, v22);
    }

    // Move the SMALLEST eigenvalue's column to position 3 (2 compare-swaps).
    v2f t;
    {
        v2i c0 = a22 > a00;            // swap cols 0,2 if col2 larger
        t = a00; a00 = sel2(c0, a22, a00); a22 = sel2(c0, t, a22);
        t = v00; v00 = sel2(c0, v02, v00); v02 = sel2(c0, -t, v02);
        t = v10; v10 = sel2(c0, v12, v10); v12 = sel2(c0, -t, v12);
        t = v20; v20 = sel2(c0, v22, v20); v22 = sel2(c0, -t, v22);
    }
    {
        v2i c1 = a22 > a11;            // swap cols 1,2 if col2 larger
        t = a11; a11 = sel2(c1, a22, a11); a22 = sel2(c1, t, a22);
        t = v01; v01 = sel2(c1, v02, v01); v02 = sel2(c1, -t, v02);
        t = v11; v11 = sel2(c1, v12, v11); v12 = sel2(c1, -t, v12);
        t = v21; v21 = sel2(c1, v22, v21); v22 = sel2(c1, -t, v22);
    }
    // Now cols 0,1 hold the two largest-sigma directions (order irrelevant).

    v2f b00 = m00*v00 + m01*v10 + m02*v20;
    v2f b10 = m10*v00 + m11*v10 + m12*v20;
    v2f b20 = m20*v00 + m21*v10 + m22*v20;
    v2f b01 = m00*v01 + m01*v11 + m02*v21;
    v2f b11 = m10*v01 + m11*v11 + m12*v21;
    v2f b21 = m20*v01 + m21*v11 + m22*v21;

    v2f n1 = b00*b00 + b10*b10 + b20*b20;
    v2f i1 = rsq2(n1);
    v2i ok1 = n1 > (v2f)1e-30f;
    i1 = sel2(ok1, i1, (v2f)0.0f);
    v2f u00 = b00*i1, u10 = b10*i1, u20 = b20*i1;

    v2f d12 = b01*u00 + b11*u10 + b21*u20;
    v2f q0 = b01 - d12*u00;
    v2f q1 = b11 - d12*u10;
    v2f q2 = b21 - d12*u20;
    v2f n2 = q0*q0 + q1*q1 + q2*q2;
    v2f i2 = rsq2(n2);
    v2i ok2 = n2 > (v2f)1e-30f;
    i2 = sel2(ok2, i2, (v2f)0.0f);
    v2f u01 = q0*i2, u11 = q1*i2, u21 = q2*i2;

    v2f u02 = u10*u21 - u20*u11;
    v2f u12 = u20*u01 - u00*u21;
    v2f u22 = u00*u11 - u10*u01;

    r00 = u00*v00 + u01*v01 + u02*v02;
    r01 = u00*v10 + u01*v11 + u02*v12;
    r02 = u00*v20 + u01*v21 + u02*v22;
    r10 = u10*v00 + u11*v01 + u12*v02;
    r11 = u10*v10 + u11*v11 + u12*v12;
    r12 = u10*v20 + u11*v21 + u12*v22;
    r20 = u20*v00 + u21*v01 + u22*v02;
    r21 = u20*v10 + u21*v11 + u22*v12;
    r22 = u20*v20 + u21*v21 + u22*v22;
}

// r17 structure (best: 30.40 us): DMA-staged wave-local double-buffered
// pipeline + non-temporal output stores. 3 sweeps restored.
__global__ __launch_bounds__(TPB) void svdo_kernel(const float* __restrict__ x,
                                                   float* __restrict__ out,
                                                   int nmat, int ntiles, int W)
{
    __shared__ float lds[4][2][FPT];     // 36864 B / block
    const int lane = threadIdx.x & 63;
    const int wv   = threadIdx.x >> 6;

    int tile = blockIdx.x * 4 + wv;
    if (tile >= ntiles) return;

    int cur = 0;
    bool full = (long)(tile + 1) * MPW <= (long)nmat;

    if (full) {
        {   // prologue: DMA tile -> buf0, drain
            const long fb = (long)tile * FPT;
            float* D = lds[wv][0];
            dma16(x + fb +        lane * 4, &D[0]);
            dma16(x + fb +  256 + lane * 4, &D[256]);
            dma16(x + fb +  512 + lane * 4, &D[512]);
            dma16(x + fb +  768 + lane * 4, &D[768]);
            dma4 (x + fb + 1024 + lane,     &D[1024]);
            dma4 (x + fb + 1088 + lane,     &D[1088]);
            asm volatile("s_waitcnt vmcnt(0)" ::: "memory");
        }

        for (;;) {
            const int  nxt   = tile + W;
            const bool have  = nxt < ntiles;
            const bool nfull = have && ((long)(nxt + 1) * MPW <= (long)nmat);

            if (nfull) {   // issue next tile's 6 DMA ops into other buffer
                const long fb = (long)nxt * FPT;
                float* D = lds[wv][cur ^ 1];
                dma16(x + fb +        lane * 4, &D[0]);
                dma16(x + fb +  256 + lane * 4, &D[256]);
                dma16(x + fb +  512 + lane * 4, &D[512]);
                dma16(x + fb +  768 + lane * 4, &D[768]);
                dma4 (x + fb + 1024 + lane,     &D[1024]);
                dma4 (x + fb + 1088 + lane,     &D[1088]);
            }

            // Compute 2 matrices from buf[cur] (stride-9 b32: 2/bank, free).
            float* L = lds[wv][cur];
            {
                const float* p0 = &L[lane * 9];
                const float* p1 = &L[(lane + 64) * 9];
                v2f m00 = {p0[0], p1[0]}, m01 = {p0[1], p1[1]}, m02 = {p0[2], p1[2]};
                v2f m10 = {p0[3], p1[3]}, m11 = {p0[4], p1[4]}, m12 = {p0[5], p1[5]};
                v2f m20 = {p0[6], p1[6]}, m21 = {p0[7], p1[7]}, m22 = {p0[8], p1[8]};

                v2f r00, r01, r02, r10, r11, r12, r20, r21, r22;
                solve2(m00, m01, m02, m10, m11, m12, m20, m21, m22,
                       r00, r01, r02, r10, r11, r12, r20, r21, r22);

                float* o0 = &L[lane * 9];
                o0[0]=r00.x; o0[1]=r01.x; o0[2]=r02.x;
                o0[3]=r10.x; o0[4]=r11.x; o0[5]=r12.x;
                o0[6]=r20.x; o0[7]=r21.x; o0[8]=r22.x;
                float* o1 = &L[(lane + 64) * 9];
                o1[0]=r00.y; o1[1]=r01.y; o1[2]=r02.y;
                o1[3]=r10.y; o1[4]=r11.y; o1[5]=r12.y;
                o1[6]=r20.y; o1[7]=r21.y; o1[8]=r22.y;
            }
            // Order writeback (ds_write) before cross-lane readout (ds_read):
            // compile-time fence; in-order per-wave DS pipe does the rest.
            asm volatile("" ::: "memory");

            // Coalesced readout + NON-TEMPORAL stores (fire-and-forget).
            {
                const long fb = (long)tile * FPT;
                f4v s0 = *(const f4v*)&L[(lane       ) * 4];
                f4v s1 = *(const f4v*)&L[(lane +  64) * 4];
                f4v s2 = *(const f4v*)&L[(lane + 128) * 4];
                f4v s3 = *(const f4v*)&L[(lane + 192) * 4];
                st_nt(out + fb + (lane       ) * 4, s0);
                st_nt(out + fb + (lane +  64) * 4, s1);
                st_nt(out + fb + (lane + 128) * 4, s2);
                st_nt(out + fb + (lane + 192) * 4, s3);
                if (lane < 32) {
                    f4v s4 = *(const f4v*)&L[(lane + 256) * 4];
                    st_nt(out + fb + (lane + 256) * 4, s4);
                }
            }

            // Drain the next tile's 6 DMA ops (older than the stores); keep
            // the 5 newest vmem ops (this iteration's stores) in flight.
            asm volatile("s_waitcnt vmcnt(5)" ::: "memory");

            if (!have) return;
            tile = nxt;
            if (!nfull) break;     // last (partial) tile -> bounded path
            cur ^= 1;
        }
    }

    // Bounded tail path (at most one partial tile; not taken at nmat=2M).
    {
        const long ntotf = (long)nmat * 9;
        const long fb = (long)tile * FPT;
        float* L = lds[wv][0];
        for (int idx = lane; idx < FPT; idx += 64) {
            long f = fb + idx;
            L[idx] = (f < ntotf) ? x[f] : 0.0f;
        }
        asm volatile("s_waitcnt vmcnt(0) lgkmcnt(0)" ::: "memory");

        const float* p0 = &L[lane * 9];
        const float* p1 = &L[(lane + 64) * 9];
        v2f m00 = {p0[0], p1[0]}, m01 = {p0[1], p1[1]}, m02 = {p0[2], p1[2]};
        v2f m10 = {p0[3], p1[3]}, m11 = {p0[4], p1[4]}, m12 = {p0[5], p1[5]};
        v2f m20 = {p0[6], p1[6]}, m21 = {p0[7], p1[7]}, m22 = {p0[8], p1[8]};
        v2f r00, r01, r02, r10, r11, r12, r20, r21, r22;
        solve2(m00, m01, m02, m10, m11, m12, m20, m21, m22,
               r00, r01, r02, r10, r11, r12, r20, r21, r22);
        float* o0 = &L[lane * 9];
        o0[0]=r00.x; o0[1]=r01.x; o0[2]=r02.x;
        o0[3]=r10.x; o0[4]=r11.x; o0[5]=r12.x;
        o0[6]=r20.x; o0[7]=r21.x; o0[8]=r22.x;
        float* o1 = &L[(lane + 64) * 9];
        o1[0]=r00.y; o1[1]=r01.y; o1[2]=r02.y;
        o1[3]=r10.y; o1[4]=r11.y; o1[5]=r12.y;
        o1[6]=r20.y; o1[7]=r21.y; o1[8]=r22.y;
        asm volatile("s_waitcnt lgkmcnt(0)" ::: "memory");

        for (int idx = lane; idx < FPT; idx += 64) {
            long f = fb + idx;
            if (f < ntotf) out[f] = L[idx];
        }
    }
}

extern "C" void kernel_launch(void* const* d_in, const int* in_sizes, int n_in,
                              void* d_out, int out_size, void* d_ws, size_t ws_size,
                              hipStream_t stream)
{
    (void)n_in; (void)d_ws; (void)ws_size; (void)out_size;
    const float* x = (const float*)d_in[0];
    float* out = (float*)d_out;
    const int nmat = in_sizes[0] / 9;
    const int ntiles = (nmat + MPW - 1) / MPW;
    int grid = (ntiles + 3) / 4;
    if (grid > 1024) grid = 1024;   // 4 blocks/CU resident (LDS), ~3.8 tiles/wave
    const int W = grid * 4;         // total waves = tile stride
    svdo_kernel<<<grid, TPB, 0, stream>>>(x, out, nmat, ntiles, W);
}